// Round 13
// baseline (104.390 us; speedup 1.0000x reference)
//
#include <hip/hip_runtime.h>
#include <hip/hip_bf16.h>

#define H_DIM   64
#define T_STEPS 128
#define B_TOT   4096
#define BB      4     // batch rows per block; grid 1024 -> 4 independent blocks/CU
#define SK      72    // padded row stride in halves for sX/sH
#define NTHREADS 256  // 4 waves; wave w owns cols w*16..w*16+15, all 4 gates
#define XBATCH  8     // x prefetch depth; must divide T_STEPS

typedef _Float16 half8  __attribute__((ext_vector_type(8)));
typedef __attribute__((ext_vector_type(4))) float f32x4;

#if __has_builtin(__builtin_amdgcn_exp2f)
#define EXP2(x) __builtin_amdgcn_exp2f(x)
#else
#define EXP2(x) exp2f(x)
#endif

// Weights/biases pre-scaled by log2(e) (i,f,o) or 2*log2(e) (g): activations
// are raw exp2-domain. c lives in the 2*log2(e)-scaled domain.
__device__ __forceinline__ float sigmoid2(float xp) {      // xp = x*log2e
    return __builtin_amdgcn_rcpf(1.0f + EXP2(-xp));        // exact at +-inf
}
__device__ __forceinline__ float tanh2(float xp) {         // xp = 2*log2e*x
    return fmaf(-2.0f, __builtin_amdgcn_rcpf(EXP2(xp) + 1.0f), 1.0f);
}

// lane l <-> l^8 exchange within each 16-lane row: row_ror:8 DPP (VALU speed).
__device__ __forceinline__ float xor8_dpp(float v) {
    return __int_as_float(__builtin_amdgcn_mov_dpp(
        __float_as_int(v), 0x128 /*row_ror:8*/, 0xf, 0xf, false));
}

// A = [x (64) | h (64)] f16, K=128, M-tile=16 with the 4 batch rows at M-rows
// {0,4,8,12} (br -> m = br*4): the valid accumulator slot is r=0 for EVERY lk,
// and batch row br == lk. ONE cell site per lane: the xor8 pair (losd, hi) at
// the same (col-octet, lk) splits the two col-halves — losd owns the cg=0 site,
// hi owns the cg=1 site. Exchange = 2 DPP xor-8 ops:
//   losd holds {i,g} for both halves, hi holds {f,o};
//   losd sends acc[cg=1] (hi's i,g), hi sends acc[cg=0] (losd's f,o).
// 4 waves/block, 4 blocks/CU -> 4 waves/SIMD each from a DIFFERENT barrier
// group (maximal phase slip), per-CU trans/LDS issue identical to R11.
__global__ __launch_bounds__(NTHREADS, 4) void lstm_fused(
    const int* __restrict__ inst, const float* __restrict__ embed,
    const float* __restrict__ Wih, const float* __restrict__ Whh,
    const float* __restrict__ bih, const float* __restrict__ bhh,
    float* __restrict__ out)
{
    __shared__ __align__(16) _Float16 sX[2][16][SK];   // 4.6 KB x staging (f16)
    __shared__ __align__(16) _Float16 sH[2][16][SK];   // 4.6 KB h staging (f16)
    __shared__ int sInst[BB * T_STEPS];                // 2 KB

    const int tid  = (int)threadIdx.x;
    const int w    = tid >> 6;          // wave 0..3; stages batch row w
    const int l    = tid & 63;
    const int lrow = l & 15;            // A-row (m) / packed-n for B & C/D
    const int lk   = l >> 4;            // k-block; C/D rows are lk*4 + 0..3
    const bool losd = (lrow < 8);       // low gate-half of the packed tile
    const int col   = w * 16 + (losd ? 0 : 8) + (lrow & 7);  // this lane's site col
    const int mrow  = lk * 4;           // LDS/M-row of the site (r = 0 slot)
    const int br    = lk;               // batch row of the site
    const int b0    = (int)blockIdx.x * BB;

    const float L2E     = 1.4426950408889634f;
    const float TWO_L2E = 2.8853900817779268f;

    // stage this block's instruction indices (4 rows x 128 steps)
    for (int i = tid; i < BB * T_STEPS; i += NTHREADS)
        sInst[i] = inst[b0 * T_STEPS + i];

    // zero all staging once: h0 = 0 AND the 12 permanently-garbage M-rows
    for (int i = tid; i < 2 * 16 * SK; i += NTHREADS) {
        ((_Float16*)sX)[i] = (_Float16)0.0f;
        ((_Float16*)sH)[i] = (_Float16)0.0f;
    }
    __syncthreads();

    // weight B-fragments (f16, exp2-prescaled): wf[cg][q][kf]
    // tile (cg,q): n=lrow -> gate q*2 + (lrow>>3), col w*16 + cg*8 + (lrow&7)
    // kf 0,1 -> W_ih k 0..63 ; kf 2,3 -> W_hh k 0..63
    half8 wf[2][2][4];
    float bias[2][2];
#pragma unroll
    for (int cg = 0; cg < 2; ++cg) {
#pragma unroll
        for (int q = 0; q < 2; ++q) {
            const int gate = q * 2 + (lrow >> 3);
            const float ws = (gate == 2) ? TWO_L2E : L2E;  // g feeds tanh(2x form)
            const int gcol = gate * 64 + w * 16 + cg * 8 + (lrow & 7);
            bias[cg][q] = (bih[gcol] + bhh[gcol]) * ws;
#pragma unroll
            for (int kf = 0; kf < 4; ++kf) {
                const float* src = (kf < 2 ? Wih : Whh) + (long)gcol * H_DIM + (kf & 1) * 32 + lk * 8;
                half8 v;
#pragma unroll
                for (int jj = 0; jj < 8; ++jj) v[jj] = (_Float16)(src[jj] * ws);
                wf[cg][q][kf] = v;
            }
        }
    }

    // x staging: wave w owns batch row w (M-row w*4), lane l owns feature l
    const int xmw = w * 4;
    {   // x(0) straight to LDS
        const int idx = sInst[w * T_STEPS + 0];
        sX[0][xmw][l] = (_Float16)embed[(long)idx * H_DIM + l];
    }

    // register x-buffer (static indices only): entry (tt-1)&7 holds x(tt)
    float xbuf[XBATCH];
#pragma unroll
    for (int j = 0; j < XBATCH; ++j) {
        const int idx = sInst[w * T_STEPS + 1 + j];
        xbuf[j] = embed[(long)idx * H_DIM + l];
    }
    __syncthreads();

    float creg = 0.f, hreg = 0.f;   // this lane's single site (br, col)

    for (int tb = 0; tb < T_STEPS; tb += XBATCH) {
#pragma unroll
        for (int j = 0; j < XBATCH; ++j) {
            const int t   = tb + j;
            const int buf = j & 1;          // tb multiple of 8 -> static parity
            const int ob  = buf ^ 1;
            const bool pf = (t + 1 < T_STEPS);

            const float xcur = xbuf[j];     // x for step t+1 (loaded >=1 step ago)

            // refill burst once per XBATCH steps: x(t+2 .. t+9)
            if (j == XBATCH - 1 && pf) {
#pragma unroll
                for (int jj = 0; jj < XBATCH; ++jj) {
                    const int tt = t + 2 + jj;
                    if (tt < T_STEPS) {
                        const int idx = sInst[w * T_STEPS + tt];
                        xbuf[jj] = embed[(long)idx * H_DIM + l];
                    }
                }
            }

            // A-fragments (f16): lane (m=lrow, lk) reads 16B contiguous
            half8 a0 = *reinterpret_cast<const half8*>(&sX[buf][lrow][lk * 8]);
            half8 a1 = *reinterpret_cast<const half8*>(&sX[buf][lrow][32 + lk * 8]);
            half8 a2 = *reinterpret_cast<const half8*>(&sH[buf][lrow][lk * 8]);
            half8 a3 = *reinterpret_cast<const half8*>(&sH[buf][lrow][32 + lk * 8]);

            // 4 packed tiles, 4 independent 4-deep MFMA chains; only slot r=0 used
            float acc[2][2];
#pragma unroll
            for (int cg = 0; cg < 2; ++cg) {
#pragma unroll
                for (int q = 0; q < 2; ++q) {
                    f32x4 a = {bias[cg][q], bias[cg][q], bias[cg][q], bias[cg][q]};
                    a = __builtin_amdgcn_mfma_f32_16x16x32_f16(a0, wf[cg][q][0], a, 0, 0, 0);
                    a = __builtin_amdgcn_mfma_f32_16x16x32_f16(a1, wf[cg][q][1], a, 0, 0, 0);
                    a = __builtin_amdgcn_mfma_f32_16x16x32_f16(a2, wf[cg][q][2], a, 0, 0, 0);
                    a = __builtin_amdgcn_mfma_f32_16x16x32_f16(a3, wf[cg][q][3], a, 0, 0, 0);
                    acc[cg][q] = a[0];
                }
            }

            // site-splitting exchange: losd owns cg=0's site, hi owns cg=1's.
            // losd holds {i,g} both halves; hi holds {f,o} both halves.
            // Send the half the partner owns; one DPP per gate-pair q.
            const float recv0 = xor8_dpp(losd ? acc[1][0] : acc[0][0]);
            const float recv1 = xor8_dpp(losd ? acc[1][1] : acc[0][1]);
            const int cgo = losd ? 0 : 1;   // own col-half
            const float vi = losd ? acc[cgo][0] : recv0;
            const float vf = losd ? recv0       : acc[cgo][0];
            const float vg = losd ? acc[cgo][1] : recv1;
            const float vo = losd ? recv1       : acc[cgo][1];

            // single-site cell update (gate order i,f,g,o), exp2 domain
            const float iv = sigmoid2(vi);
            const float fv = sigmoid2(vf);
            const float gv = tanh2(vg);
            const float ov = sigmoid2(vo);
            const float cs = fmaf(fv, creg, iv * (gv * TWO_L2E));  // scaled-c domain
            creg = cs;
            hreg = ov * tanh2(cs);

            if (pf) {
                sH[ob][mrow][col] = (_Float16)hreg;    // publish h (f16, RNE)
                sX[ob][xmw][l]    = (_Float16)xcur;    // publish prefetched x
            }
            __syncthreads();   // sX/sH[ob] visible before next step
        }
    }

    // final h (f32) -> out[B][H]; one element per lane
    out[(long)(b0 + br) * H_DIM + col] = hreg;
}

extern "C" void kernel_launch(void* const* d_in, const int* in_sizes, int n_in,
                              void* d_out, int out_size, void* d_ws, size_t ws_size,
                              hipStream_t stream) {
    const int*   inst  = (const int*)  d_in[0];
    const float* embed = (const float*)d_in[1];
    const float* Wih   = (const float*)d_in[2];
    const float* Whh   = (const float*)d_in[3];
    const float* bih   = (const float*)d_in[4];
    const float* bhh   = (const float*)d_in[5];
    float* out = (float*)d_out;

    lstm_fused<<<B_TOT / BB, NTHREADS, 0, stream>>>(inst, embed, Wih, Whh, bih, bhh, out);
}

// Round 14
// 86.343 us; speedup vs baseline: 1.2090x; 1.2090x over previous
//
#include <hip/hip_runtime.h>
#include <hip/hip_bf16.h>

#define H_DIM   64
#define T_STEPS 128
#define B_TOT   4096
#define BB      8     // batch rows per block; 512 blocks -> 2 independent blocks/CU
#define SK      72    // padded row stride in halves for sX/sH
#define NTHREADS 512  // 8 waves; wave w owns cols w*8..w*8+7 (both gate halves)
#define XBATCH  8     // x prefetch depth; must divide T_STEPS

typedef _Float16 half8  __attribute__((ext_vector_type(8)));
typedef __attribute__((ext_vector_type(4))) float f32x4;

#if __has_builtin(__builtin_amdgcn_exp2f)
#define EXP2(x) __builtin_amdgcn_exp2f(x)
#else
#define EXP2(x) exp2f(x)
#endif
#define RCP(x) __builtin_amdgcn_rcpf(x)

// lane l <-> l^8 exchange within each 16-lane row: row_ror:8 DPP (VALU speed).
__device__ __forceinline__ float xor8_dpp(float v) {
    return __int_as_float(__builtin_amdgcn_mov_dpp(
        __float_as_int(v), 0x128 /*row_ror:8*/, 0xf, 0xf, false));
}

// A = [x (64) | h (64)] f16, K=128, M-tile=16 with the 8 batch rows placed at
// M-rows {0,1,4,5,8,9,12,13} (br -> m = (br>>1)*4 + (br&1)) so the valid
// accumulator slots are r in {0,1} for EVERY lk. ONE cell site per lane.
// Weights pre-scaled into exp2 domain: i,f,o by log2(e); g by 2*log2(e);
// c lives in the 2*log2(e)-scaled domain.
//
// Merged-reciprocal cell update (exact algebra, 5 exp + 2 rcp per site):
//   Ei=2^-i', Ef=2^-f', Eg=2^g'', Eo=2^-o'
//   P=(1+Ei)(Eg+1); R=rcp(P*(1+Ef)); fv=P*R; iv*gv=(Eg-1)*(1+Ef)*R
//   cs=fv*c + iv*gv*2log2e ; Eh=2^min(cs,126)
//   h = (Eh-1)*rcp((Eh+1)(1+Eo))        [= tanh(c)*sigmoid(o)]
__global__ __launch_bounds__(NTHREADS, 4) void lstm_fused(
    const int* __restrict__ inst, const float* __restrict__ embed,
    const float* __restrict__ Wih, const float* __restrict__ Whh,
    const float* __restrict__ bih, const float* __restrict__ bhh,
    float* __restrict__ out)
{
    __shared__ __align__(16) _Float16 sX[2][16][SK];   // 4.6 KB x staging (f16)
    __shared__ __align__(16) _Float16 sH[2][16][SK];   // 4.6 KB h staging (f16)
    __shared__ int sInst[BB * T_STEPS];                // 4 KB

    const int tid  = (int)threadIdx.x;
    const int w    = tid >> 6;          // wave 0..7; also this wave's x-staging row
    const int l    = tid & 63;
    const int lrow = l & 15;            // A-row (m) / packed-n for B & C/D
    const int lk   = l >> 4;            // k-block; C/D rows are lk*4 + 0..3
    const bool losd = (lrow < 8);       // low gate-half of the packed tile
    const int col   = w * 8 + (lrow & 7);  // h-column of this lane's site
    const int rstar = losd ? 0 : 1;     // row-slot this lane owns
    const int mrow  = lk * 4 + rstar;   // LDS/M-row of the site
    const int br    = lk * 2 + rstar;   // batch row of the site
    const int b0    = (int)blockIdx.x * BB;

    const float L2E     = 1.4426950408889634f;
    const float TWO_L2E = 2.8853900817779268f;

    // stage this block's instruction indices (8 rows x 128 steps)
    for (int i = tid; i < BB * T_STEPS; i += NTHREADS)
        sInst[i] = inst[b0 * T_STEPS + i];

    // zero all staging once: h0 = 0 AND the 8 permanently-garbage M-rows
    for (int i = tid; i < 2 * 16 * SK; i += NTHREADS) {
        ((_Float16*)sX)[i] = (_Float16)0.0f;
        ((_Float16*)sH)[i] = (_Float16)0.0f;
    }
    __syncthreads();

    // weight B-fragments (f16, exp2-prescaled): tile q -> gate q*2 + (lrow>>3)
    // kf 0,1 -> W_ih k 0..63 ; kf 2,3 -> W_hh k 0..63
    half8 wf[2][4];
    float bias[2];
#pragma unroll
    for (int q = 0; q < 2; ++q) {
        const int gate = q * 2 + (lrow >> 3);
        const float ws = (gate == 2) ? TWO_L2E : L2E;  // g feeds tanh(2x form)
        const int gcol = gate * 64 + col;              // W output row 0..255
        bias[q] = (bih[gcol] + bhh[gcol]) * ws;
#pragma unroll
        for (int kf = 0; kf < 4; ++kf) {
            const float* src = (kf < 2 ? Wih : Whh) + (long)gcol * H_DIM + (kf & 1) * 32 + lk * 8;
            half8 v;
#pragma unroll
            for (int jj = 0; jj < 8; ++jj) v[jj] = (_Float16)(src[jj] * ws);
            wf[q][kf] = v;
        }
    }

    // x staging: wave w owns batch row w (M-row xmw), lane l owns feature l
    const int xmw = (w >> 1) * 4 + (w & 1);
    {   // x(0) straight to LDS
        const int idx = sInst[w * T_STEPS + 0];
        sX[0][xmw][l] = (_Float16)embed[(long)idx * H_DIM + l];
    }

    // register x-buffer (static indices only): entry (tt-1)&7 holds x(tt)
    float xbuf[XBATCH];
#pragma unroll
    for (int j = 0; j < XBATCH; ++j) {
        const int idx = sInst[w * T_STEPS + 1 + j];
        xbuf[j] = embed[(long)idx * H_DIM + l];
    }
    __syncthreads();

    float creg = 0.f, hreg = 0.f;   // this lane's single site (br, col)

    for (int tb = 0; tb < T_STEPS; tb += XBATCH) {
#pragma unroll
        for (int j = 0; j < XBATCH; ++j) {
            const int t   = tb + j;
            const int buf = j & 1;          // tb multiple of 8 -> static parity
            const int ob  = buf ^ 1;
            const bool pf = (t + 1 < T_STEPS);

            const float xcur = xbuf[j];     // x for step t+1 (loaded >=1 step ago)

            // refill burst once per XBATCH steps: x(t+2 .. t+9)
            if (j == XBATCH - 1 && pf) {
#pragma unroll
                for (int jj = 0; jj < XBATCH; ++jj) {
                    const int tt = t + 2 + jj;
                    if (tt < T_STEPS) {
                        const int idx = sInst[w * T_STEPS + tt];
                        xbuf[jj] = embed[(long)idx * H_DIM + l];
                    }
                }
            }

            // A-fragments (f16): lane (m=lrow, lk) reads 16B contiguous
            half8 a0 = *reinterpret_cast<const half8*>(&sX[buf][lrow][lk * 8]);
            half8 a1 = *reinterpret_cast<const half8*>(&sX[buf][lrow][32 + lk * 8]);
            half8 a2 = *reinterpret_cast<const half8*>(&sH[buf][lrow][lk * 8]);
            half8 a3 = *reinterpret_cast<const half8*>(&sH[buf][lrow][32 + lk * 8]);

            // 2 packed gate-pair tiles; x-chain and h-chain split so the
            // x MFMAs issue under the h ds_read wait and stay off the
            // h-dependent critical path.
            __builtin_amdgcn_s_setprio(1);
            f32x4 acc[2];
#pragma unroll
            for (int q = 0; q < 2; ++q) {
                f32x4 pX = {bias[q], bias[q], bias[q], bias[q]};
                f32x4 pH = {0.f, 0.f, 0.f, 0.f};
                pX = __builtin_amdgcn_mfma_f32_16x16x32_f16(a0, wf[q][0], pX, 0, 0, 0);
                pX = __builtin_amdgcn_mfma_f32_16x16x32_f16(a1, wf[q][1], pX, 0, 0, 0);
                pH = __builtin_amdgcn_mfma_f32_16x16x32_f16(a2, wf[q][2], pH, 0, 0, 0);
                pH = __builtin_amdgcn_mfma_f32_16x16x32_f16(a3, wf[q][3], pH, 0, 0, 0);
                acc[q] = pX + pH;
            }
            __builtin_amdgcn_s_setprio(0);

            // site-splitting exchange: losd owns slot 0, hi owns slot 1.
            const float recv0 = xor8_dpp(losd ? acc[0][1] : acc[0][0]);
            const float recv1 = xor8_dpp(losd ? acc[1][1] : acc[1][0]);
            const float vi = losd ? acc[0][0] : recv0;
            const float vf = losd ? recv0     : acc[0][1];
            const float vg = losd ? acc[1][0] : recv1;
            const float vo = losd ? recv1     : acc[1][1];

            // publish prefetched x early (independent of the activation tail)
            if (pf) sX[ob][xmw][l] = (_Float16)xcur;

            // merged-reciprocal cell update: 5 exp + 2 rcp
            const float Ei = EXP2(-vi);
            const float Ef = EXP2(-vf);
            const float Eg = EXP2(vg);
            const float Eo = EXP2(-vo);
            const float oneEf = 1.0f + Ef;
            const float P  = (1.0f + Ei) * (Eg + 1.0f);
            const float R  = RCP(P * oneEf);
            const float fv = P * R;                       // sigmoid(f)
            const float ivgv = (Eg - 1.0f) * (oneEf * R); // sigmoid(i)*tanh(g)
            const float cs = fmaf(fv, creg, ivgv * TWO_L2E);  // scaled-c domain
            creg = cs;
            const float Eh = EXP2(fminf(cs, 126.0f));     // guard inf*0 -> NaN
            const float rq = RCP((Eh + 1.0f) * (1.0f + Eo));
            hreg = (Eh - 1.0f) * rq;                      // tanh(c)*sigmoid(o)

            if (pf) sH[ob][mrow][col] = (_Float16)hreg;   // publish h (f16, RNE)
            __syncthreads();   // sX/sH[ob] visible before next step
        }
    }

    // final h (f32) -> out[B][H]; one element per lane
    out[(long)(b0 + br) * H_DIM + col] = hreg;
}

extern "C" void kernel_launch(void* const* d_in, const int* in_sizes, int n_in,
                              void* d_out, int out_size, void* d_ws, size_t ws_size,
                              hipStream_t stream) {
    const int*   inst  = (const int*)  d_in[0];
    const float* embed = (const float*)d_in[1];
    const float* Wih   = (const float*)d_in[2];
    const float* Whh   = (const float*)d_in[3];
    const float* bih   = (const float*)d_in[4];
    const float* bhh   = (const float*)d_in[5];
    float* out = (float*)d_out;

    lstm_fused<<<B_TOT / BB, NTHREADS, 0, stream>>>(inst, embed, Wih, Whh, bih, bhh, out);
}

// Round 15
// 81.510 us; speedup vs baseline: 1.2807x; 1.0593x over previous
//
#include <hip/hip_runtime.h>
#include <hip/hip_bf16.h>

#define H_DIM   64
#define T_STEPS 128
#define B_TOT   4096
#define BB      8     // batch rows per block; 512 blocks -> 2 independent blocks/CU
#define SK      72    // padded row stride in halves for sX/sH
#define NTHREADS 512  // 8 waves; wave w owns cols w*8..w*8+7 (both gate halves)
#define XBATCH  8     // x prefetch depth; must divide T_STEPS

typedef _Float16 half8  __attribute__((ext_vector_type(8)));
typedef __attribute__((ext_vector_type(4))) float f32x4;

#if __has_builtin(__builtin_amdgcn_exp2f)
#define EXP2(x) __builtin_amdgcn_exp2f(x)
#else
#define EXP2(x) exp2f(x)
#endif
#define RCP(x) __builtin_amdgcn_rcpf(x)

// In-loop barrier WITHOUT the __syncthreads vmcnt(0) drain: cross-wave deps in
// this kernel are LDS-only, so lgkmcnt(0) + s_barrier is sufficient (m201
// pattern). Memory-clobber fences pin LDS ops on both sides.
#define BLOCK_SYNC() do {                                      \
    asm volatile("s_waitcnt lgkmcnt(0)" ::: "memory");         \
    __builtin_amdgcn_s_barrier();                              \
    asm volatile("" ::: "memory");                             \
} while (0)

// Weights/biases pre-scaled by log2(e) (i,f,o) or 2*log2(e) (g): activations
// are raw exp2-domain. c lives in the 2*log2(e)-scaled domain.
__device__ __forceinline__ float sigmoid2(float xp) {      // xp = x*log2e
    return RCP(1.0f + EXP2(-xp));                          // exact at +-inf
}
__device__ __forceinline__ float tanh2(float xp) {         // xp = 2*log2e*x
    return fmaf(-2.0f, RCP(EXP2(xp) + 1.0f), 1.0f);
}

// lane l <-> l^8 exchange within each 16-lane row: row_ror:8 DPP (VALU speed).
__device__ __forceinline__ float xor8_dpp(float v) {
    return __int_as_float(__builtin_amdgcn_mov_dpp(
        __float_as_int(v), 0x128 /*row_ror:8*/, 0xf, 0xf, false));
}

// R11 geometry: A = [x|h] f16 K=128, M-tile=16, batch rows at M-rows
// {0,1,4,5,8,9,12,13}; ONE cell site per lane; gate exchange = 2 DPP xor-8.
// NEW: x-projection runs one step ahead. sX[ob] holds x(t+1) (published at
// t-1), sX[buf] receives x(t+2); xacc(t+1) = bias + x(t+1)*W_ih is computed
// off-path at step t, so the critical recurrence is only:
//   barrier -> ds_read(h) -> 2 h-MFMAs -> DPP -> activations -> ds_write -> barrier
__global__ __launch_bounds__(NTHREADS, 4) void lstm_fused(
    const int* __restrict__ inst, const float* __restrict__ embed,
    const float* __restrict__ Wih, const float* __restrict__ Whh,
    const float* __restrict__ bih, const float* __restrict__ bhh,
    float* __restrict__ out)
{
    __shared__ __align__(16) _Float16 sX[2][16][SK];   // 4.6 KB x staging (f16)
    __shared__ __align__(16) _Float16 sH[2][16][SK];   // 4.6 KB h staging (f16)
    __shared__ int sInst[BB * T_STEPS];                // 4 KB

    const int tid  = (int)threadIdx.x;
    const int w    = tid >> 6;          // wave 0..7; also this wave's x-staging row
    const int l    = tid & 63;
    const int lrow = l & 15;            // A-row (m) / packed-n for B & C/D
    const int lk   = l >> 4;            // k-block; C/D rows are lk*4 + 0..3
    const bool losd = (lrow < 8);       // low gate-half of the packed tile
    const int col   = w * 8 + (lrow & 7);  // h-column of this lane's site
    const int rstar = losd ? 0 : 1;     // row-slot this lane owns
    const int mrow  = lk * 4 + rstar;   // LDS/M-row of the site
    const int br    = lk * 2 + rstar;   // batch row of the site
    const int b0    = (int)blockIdx.x * BB;

    const float L2E     = 1.4426950408889634f;
    const float TWO_L2E = 2.8853900817779268f;

    // stage this block's instruction indices (8 rows x 128 steps)
    for (int i = tid; i < BB * T_STEPS; i += NTHREADS)
        sInst[i] = inst[b0 * T_STEPS + i];

    // zero all staging once: h0 = 0 AND the 8 permanently-garbage M-rows
    for (int i = tid; i < 2 * 16 * SK; i += NTHREADS) {
        ((_Float16*)sX)[i] = (_Float16)0.0f;
        ((_Float16*)sH)[i] = (_Float16)0.0f;
    }
    __syncthreads();

    // weight B-fragments (f16, exp2-prescaled): tile q -> gate q*2 + (lrow>>3)
    // kf 0,1 -> W_ih k 0..63 ; kf 2,3 -> W_hh k 0..63
    half8 wf[2][4];
    float bias[2];
#pragma unroll
    for (int q = 0; q < 2; ++q) {
        const int gate = q * 2 + (lrow >> 3);
        const float ws = (gate == 2) ? TWO_L2E : L2E;  // g feeds tanh(2x form)
        const int gcol = gate * 64 + col;              // W output row 0..255
        bias[q] = (bih[gcol] + bhh[gcol]) * ws;
#pragma unroll
        for (int kf = 0; kf < 4; ++kf) {
            const float* src = (kf < 2 ? Wih : Whh) + (long)gcol * H_DIM + (kf & 1) * 32 + lk * 8;
            half8 v;
#pragma unroll
            for (int jj = 0; jj < 8; ++jj) v[jj] = (_Float16)(src[jj] * ws);
            wf[q][kf] = v;
        }
    }

    // x staging: wave w owns batch row w (M-row xmw), lane l owns feature l
    const int xmw = (w >> 1) * 4 + (w & 1);
    {   // x(0) -> sX[0], x(1) -> sX[1]
        const int i0 = sInst[w * T_STEPS + 0];
        sX[0][xmw][l] = (_Float16)embed[(long)i0 * H_DIM + l];
        const int i1 = sInst[w * T_STEPS + 1];
        sX[1][xmw][l] = (_Float16)embed[(long)i1 * H_DIM + l];
    }

    // register x-buffer (static indices only): xbuf[j] holds x(tb + j + 2)
    float xbuf[XBATCH];
#pragma unroll
    for (int j = 0; j < XBATCH; ++j) {
        const int idx = sInst[w * T_STEPS + 2 + j];
        xbuf[j] = embed[(long)idx * H_DIM + l];
    }
    __syncthreads();

    // prologue: xacc for step 0 (slot 0) from x(0) in sX[0]
    f32x4 xacc0[2], xacc1[2];
    {
        half8 ax0 = *reinterpret_cast<const half8*>(&sX[0][lrow][lk * 8]);
        half8 ax1 = *reinterpret_cast<const half8*>(&sX[0][lrow][32 + lk * 8]);
#pragma unroll
        for (int q = 0; q < 2; ++q) {
            f32x4 a = {bias[q], bias[q], bias[q], bias[q]};
            a = __builtin_amdgcn_mfma_f32_16x16x32_f16(ax0, wf[q][0], a, 0, 0, 0);
            a = __builtin_amdgcn_mfma_f32_16x16x32_f16(ax1, wf[q][1], a, 0, 0, 0);
            xacc0[q] = a;
        }
    }

    float creg = 0.f, hreg = 0.f;   // this lane's single site (br, col)

    for (int tb = 0; tb < T_STEPS; tb += XBATCH) {
#pragma unroll
        for (int j = 0; j < XBATCH; ++j) {
            const int t   = tb + j;
            const int buf = j & 1;          // tb multiple of 8 -> static parity
            const int ob  = buf ^ 1;
            const bool pf = (t + 1 < T_STEPS);

            // CRITICAL PATH: h(t) fragments first
            half8 a2 = *reinterpret_cast<const half8*>(&sH[buf][lrow][lk * 8]);
            half8 a3 = *reinterpret_cast<const half8*>(&sH[buf][lrow][32 + lk * 8]);

            // refill burst once per XBATCH steps: x(t+3 .. t+10) for next block
            if (j == XBATCH - 1) {
#pragma unroll
                for (int jj = 0; jj < XBATCH; ++jj) {
                    const int tt = t + 3 + jj;
                    if (tt < T_STEPS) {
                        const int idx = sInst[w * T_STEPS + tt];
                        xbuf[jj] = embed[(long)idx * H_DIM + l];
                    }
                }
            }

            // gates = xacc(t) + h(t)*W_hh : only 2 MFMAs deep on the recurrence
            f32x4 acc[2];
#pragma unroll
            for (int q = 0; q < 2; ++q) {
                f32x4 a = (j & 1) ? xacc1[q] : xacc0[q];   // j static -> reg select
                a = __builtin_amdgcn_mfma_f32_16x16x32_f16(a2, wf[q][2], a, 0, 0, 0);
                a = __builtin_amdgcn_mfma_f32_16x16x32_f16(a3, wf[q][3], a, 0, 0, 0);
                acc[q] = a;
            }

            // OFF-PATH: xacc(t+1) = bias + x(t+1)*W_ih from sX[ob]
            if (pf) {
                half8 ax0 = *reinterpret_cast<const half8*>(&sX[ob][lrow][lk * 8]);
                half8 ax1 = *reinterpret_cast<const half8*>(&sX[ob][lrow][32 + lk * 8]);
#pragma unroll
                for (int q = 0; q < 2; ++q) {
                    f32x4 a = {bias[q], bias[q], bias[q], bias[q]};
                    a = __builtin_amdgcn_mfma_f32_16x16x32_f16(ax0, wf[q][0], a, 0, 0, 0);
                    a = __builtin_amdgcn_mfma_f32_16x16x32_f16(ax1, wf[q][1], a, 0, 0, 0);
                    if (j & 1) xacc0[q] = a; else xacc1[q] = a;  // j static
                }
            }

            // site-splitting exchange: losd owns slot 0, hi owns slot 1.
            const float recv0 = xor8_dpp(losd ? acc[0][1] : acc[0][0]);
            const float recv1 = xor8_dpp(losd ? acc[1][1] : acc[1][0]);
            const float vi = losd ? acc[0][0] : recv0;
            const float vf = losd ? recv0     : acc[0][1];
            const float vg = losd ? acc[1][0] : recv1;
            const float vo = losd ? recv1     : acc[1][1];

            // single-site cell update (gate order i,f,g,o), exp2 domain (R11 form)
            const float iv = sigmoid2(vi);
            const float fv = sigmoid2(vf);
            const float gv = tanh2(vg);
            const float ov = sigmoid2(vo);
            const float cs = fmaf(fv, creg, iv * (gv * TWO_L2E));  // scaled-c domain
            creg = cs;
            hreg = ov * tanh2(cs);

            // publishes: h(t+1) -> sH[ob]; x(t+2) -> sX[buf] (consumed at t+1)
            if (pf)
                sH[ob][mrow][col] = (_Float16)hreg;
            if (t + 2 < T_STEPS)
                sX[buf][xmw][l] = (_Float16)xbuf[j];

            BLOCK_SYNC();   // lgkmcnt-only barrier: x-refill loads stay in flight
        }
    }

    // final h (f32) -> out[B][H]; one element per lane
    out[(long)(b0 + br) * H_DIM + col] = hreg;
}

extern "C" void kernel_launch(void* const* d_in, const int* in_sizes, int n_in,
                              void* d_out, int out_size, void* d_ws, size_t ws_size,
                              hipStream_t stream) {
    const int*   inst  = (const int*)  d_in[0];
    const float* embed = (const float*)d_in[1];
    const float* Wih   = (const float*)d_in[2];
    const float* Whh   = (const float*)d_in[3];
    const float* bih   = (const float*)d_in[4];
    const float* bhh   = (const float*)d_in[5];
    float* out = (float*)d_out;

    lstm_fused<<<B_TOT / BB, NTHREADS, 0, stream>>>(inst, embed, Wih, Whh, bih, bhh, out);
}